// Round 1
// baseline (414.688 us; speedup 1.0000x reference)
//
#include <hip/hip_runtime.h>
#include <cstdint>

#define HB 2
#define HS 1024
#define HSF 2048
#define HH 16
#define HDH 128
#define HD 2048
#define HD3 6144
#define HM 2048  // HB*HS

typedef __attribute__((ext_vector_type(8))) short bf16x8;
typedef __attribute__((ext_vector_type(4))) float f32x4;
typedef unsigned short u16;
typedef unsigned int u32;

__device__ __forceinline__ u16 f2b(float f) {
    union { float f; u32 u; } v; v.f = f;
    u32 u = v.u;
    return (u16)((u + 0x7FFFu + ((u >> 16) & 1u)) >> 16);
}

__device__ __forceinline__ f32x4 mfma16x16(bf16x8 a, bf16x8 b, f32x4 c) {
    return __builtin_amdgcn_mfma_f32_16x16x32_bf16(a, b, c, 0, 0, 0);
}

#define GLD16(gp, lp) __builtin_amdgcn_global_load_lds( \
    (__attribute__((address_space(1))) void*)(gp), \
    (__attribute__((address_space(3))) void*)(lp), 16, 0, 0)

// ---------------- cast f32 -> bf16 (vectorized) ----------------
__global__ void k_cast(const float* __restrict__ src, u16* __restrict__ dst, int n4) {
    int i = blockIdx.x * blockDim.x + threadIdx.x;
    int st = gridDim.x * blockDim.x;
    for (; i < n4; i += st) {
        float4 v = ((const float4*)src)[i];
        ushort4 o;
        o.x = f2b(v.x); o.y = f2b(v.y); o.z = f2b(v.z); o.w = f2b(v.w);
        ((ushort4*)dst)[i] = o;
    }
}

// ---------------- copy caches into outputs + bf16 K + bf16 V^T ----------------
__global__ void k_cache_copy(const float* __restrict__ kc, const float* __restrict__ vc,
                             float* __restrict__ kf, float* __restrict__ vf,
                             u16* __restrict__ kb, u16* __restrict__ vt) {
    const int n4 = HB * HH * HS * HDH / 4;
    int i = blockIdx.x * blockDim.x + threadIdx.x;
    int st = gridDim.x * blockDim.x;
    for (; i < n4; i += st) {
        int e = i * 4;
        int bh = e / (HS * HDH);
        int rem = e - bh * (HS * HDH);   // s*128 + dh
        int s = rem >> 7, dh = rem & 127;
        float4 kv = ((const float4*)kc)[i];
        float4 vv = ((const float4*)vc)[i];
        size_t o = (size_t)bh * (HSF * HDH) + (size_t)rem;
        *(float4*)(kf + o) = kv;
        *(float4*)(vf + o) = vv;
        ushort4 kb4; kb4.x = f2b(kv.x); kb4.y = f2b(kv.y); kb4.z = f2b(kv.z); kb4.w = f2b(kv.w);
        *(ushort4*)(kb + o) = kb4;
        size_t vb = (size_t)bh * (HDH * HSF) + (size_t)dh * HSF + (size_t)s;
        vt[vb]           = f2b(vv.x);
        vt[vb + HSF]     = f2b(vv.y);
        vt[vb + 2 * HSF] = f2b(vv.z);
        vt[vb + 3 * HSF] = f2b(vv.w);
    }
}

// ---------------- bf16 GEMM: C[m,n] = sum_k A[m,k]*B[n,k] ----------------
// EPI=0: QKV scatter epilogue (N=6144).  EPI=1: plain fp32 C write (N=2048).
template<int EPI>
__global__ __launch_bounds__(256, 2) void k_gemm_bt(
    const u16* __restrict__ A, const u16* __restrict__ Bw, int K,
    float* __restrict__ outf,
    u16* __restrict__ qb, float* __restrict__ kf, float* __restrict__ vf,
    u16* __restrict__ kb, u16* __restrict__ vt)
{
    __shared__ __align__(16) u16 As[128 * 32];
    __shared__ __align__(16) u16 Bs[128 * 32];
    const int tid = threadIdx.x;
    const int w = tid >> 6, lane = tid & 63;
    const int wm = w >> 1, wn = w & 1;
    const int lcol = lane & 15, lhi = lane >> 4;
    const int m0 = blockIdx.x * 128, n0 = blockIdx.y * 128;

    const int srow = lane >> 2;        // 0..15
    const int scol = (lane & 3) * 8;   // 0,8,16,24
    const int c0 = w * 2, c1 = w * 2 + 1;
    const u16* Ag0 = A + (size_t)(m0 + c0 * 16 + srow) * K + scol;
    const u16* Ag1 = A + (size_t)(m0 + c1 * 16 + srow) * K + scol;
    const u16* Bg0 = Bw + (size_t)(n0 + c0 * 16 + srow) * K + scol;
    const u16* Bg1 = Bw + (size_t)(n0 + c1 * 16 + srow) * K + scol;
    u16* As0 = &As[c0 * 512]; u16* As1 = &As[c1 * 512];
    u16* Bs0 = &Bs[c0 * 512]; u16* Bs1 = &Bs[c1 * 512];

    f32x4 acc[4][4] = {};

    for (int k0 = 0; k0 < K; k0 += 32) {
        __syncthreads();
        GLD16(Ag0 + k0, As0);
        GLD16(Ag1 + k0, As1);
        GLD16(Bg0 + k0, Bs0);
        GLD16(Bg1 + k0, Bs1);
        __syncthreads();
        bf16x8 af[4], bfr[4];
        #pragma unroll
        for (int i = 0; i < 4; ++i)
            af[i] = *(const bf16x8*)&As[(wm * 64 + i * 16 + lcol) * 32 + lhi * 8];
        #pragma unroll
        for (int i = 0; i < 4; ++i)
            bfr[i] = *(const bf16x8*)&Bs[(wn * 64 + i * 16 + lcol) * 32 + lhi * 8];
        #pragma unroll
        for (int i = 0; i < 4; ++i)
            #pragma unroll
            for (int j = 0; j < 4; ++j)
                acc[i][j] = mfma16x16(af[i], bfr[j], acc[i][j]);
    }

    #pragma unroll
    for (int i = 0; i < 4; ++i) {
      #pragma unroll
      for (int j = 0; j < 4; ++j) {
        #pragma unroll
        for (int r = 0; r < 4; ++r) {
            int m = m0 + wm * 64 + i * 16 + lhi * 4 + r;
            int n = n0 + wn * 64 + j * 16 + lcol;
            float v = acc[i][j][r];
            if (EPI == 1) {
                outf[(size_t)m * HD + n] = v;
            } else {
                int b = m >> 10, s = m & 1023;
                int sec = n >> 11, e = n & 2047;
                int h = e >> 7, dh = e & 127;
                int bh = b * HH + h;
                if (sec == 0) {
                    qb[((size_t)bh * HS + s) * HDH + dh] = f2b(v);
                } else if (sec == 1) {
                    size_t idx = ((size_t)bh * HSF + HS + s) * HDH + dh;
                    kf[idx] = v; kb[idx] = f2b(v);
                } else {
                    size_t idx = ((size_t)bh * HSF + HS + s) * HDH + dh;
                    vf[idx] = v;
                    vt[((size_t)bh * HDH + dh) * HSF + HS + s] = f2b(v);
                }
            }
        }
      }
    }
}

// ---------------- flash attention: 1 wave = 16 q rows ----------------
__global__ __launch_bounds__(256, 2) void k_attn(
    const u16* __restrict__ qb, const u16* __restrict__ kb,
    const u16* __restrict__ vt, u16* __restrict__ ctx,
    const int* __restrict__ plp)
{
    __shared__ __align__(16) u16 Pl[4][16][40];
    const int past = *plp;                 // 1024
    const int tid = threadIdx.x, w = tid >> 6, lane = tid & 63;
    const int lcol = lane & 15, lhi = lane >> 4;
    const int bh = blockIdx.y;             // 0..31
    const int q0 = blockIdx.x * 64 + w * 16;
    const float sc2 = 0.08838834764831845f * 1.4426950408889634f; // scale * log2(e)

    const u16* qrow = qb + (size_t)bh * HS * HDH;
    const u16* kx = kb + (size_t)bh * HSF * HDH;
    const u16* vx = vt + (size_t)bh * HDH * HSF;

    bf16x8 aq[4];
    #pragma unroll
    for (int kc = 0; kc < 4; ++kc)
        aq[kc] = *(const bf16x8*)&qrow[(size_t)(q0 + lcol) * HDH + kc * 32 + lhi * 8];

    f32x4 o[8] = {};
    float mr[4], lr[4];
    #pragma unroll
    for (int r = 0; r < 4; ++r) { mr[r] = -3e38f; lr[r] = 0.f; }

    int nkt = (blockIdx.x * 64 + 64 + past + 31) >> 5;
    if (nkt > HSF / 32) nkt = HSF / 32;

    for (int kt = 0; kt < nkt; ++kt) {
        const int j0 = kt * 32;
        // ---- QK^T ----
        bf16x8 bk[2][4];
        #pragma unroll
        for (int sub = 0; sub < 2; ++sub)
            #pragma unroll
            for (int kc = 0; kc < 4; ++kc)
                bk[sub][kc] = *(const bf16x8*)&kx[(size_t)(j0 + sub * 16 + lcol) * HDH + kc * 32 + lhi * 8];
        f32x4 sf[2] = {};
        #pragma unroll
        for (int sub = 0; sub < 2; ++sub)
            #pragma unroll
            for (int kc = 0; kc < 4; ++kc)
                sf[sub] = mfma16x16(aq[kc], bk[sub][kc], sf[sub]);

        // ---- masked online softmax (exp2 domain) ----
        float al[4];
        #pragma unroll
        for (int r = 0; r < 4; ++r) {
            int q = q0 + lhi * 4 + r;
            float s0 = sf[0][r] * sc2;
            float s1 = sf[1][r] * sc2;
            if (j0 + lcol > q + past)      s0 = -3e38f;
            if (j0 + 16 + lcol > q + past) s1 = -3e38f;
            float mx = fmaxf(s0, s1);
            #pragma unroll
            for (int sh = 1; sh < 16; sh <<= 1) mx = fmaxf(mx, __shfl_xor(mx, sh, 64));
            float mnew = fmaxf(mr[r], mx);
            float alpha = exp2f(mr[r] - mnew);
            float p0 = exp2f(s0 - mnew);
            float p1 = exp2f(s1 - mnew);
            float ps = p0 + p1;
            #pragma unroll
            for (int sh = 1; sh < 16; sh <<= 1) ps += __shfl_xor(ps, sh, 64);
            lr[r] = lr[r] * alpha + ps;
            mr[r] = mnew;
            al[r] = alpha;
            Pl[w][lhi * 4 + r][lcol]      = f2b(p0);
            Pl[w][lhi * 4 + r][16 + lcol] = f2b(p1);
        }
        #pragma unroll
        for (int d = 0; d < 8; ++d) {
            f32x4 t = o[d];
            t[0] *= al[0]; t[1] *= al[1]; t[2] *= al[2]; t[3] *= al[3];
            o[d] = t;
        }

        // ---- PV ----  (same-wave DS write->read: DS pipe is in-order per wave)
        bf16x8 ap = *(const bf16x8*)&Pl[w][lcol][lhi * 8];
        #pragma unroll
        for (int d = 0; d < 8; ++d) {
            bf16x8 bv = *(const bf16x8*)&vx[(size_t)(d * 16 + lcol) * HSF + j0 + lhi * 8];
            o[d] = mfma16x16(ap, bv, o[d]);
        }
    }

    const int b = bh >> 4, h = bh & 15;
    #pragma unroll
    for (int r = 0; r < 4; ++r) {
        float inv = 1.f / lr[r];
        int s = q0 + lhi * 4 + r;
        #pragma unroll
        for (int d = 0; d < 8; ++d)
            ctx[((size_t)(b * HS + s)) * HD + h * HDH + d * 16 + lcol] = f2b(o[d][r] * inv);
    }
}

// ---------------- launch ----------------
extern "C" void kernel_launch(void* const* d_in, const int* in_sizes, int n_in,
                              void* d_out, int out_size, void* d_ws, size_t ws_size,
                              hipStream_t stream) {
    const float* x   = (const float*)d_in[0];
    const float* kc  = (const float*)d_in[1];
    const float* vc  = (const float*)d_in[2];
    const float* qkv = (const float*)d_in[3];
    const float* wo  = (const float*)d_in[4];
    const int* plp   = (const int*)d_in[5];

    float* out = (float*)d_out;
    float* kf  = out + (size_t)HB * HS * HD;        // k_full: 8,388,608 floats
    float* vf  = kf + (size_t)HB * HH * HSF * HDH;  // v_full

    char* ws = (char*)d_ws;
    size_t o1 = (size_t)HM * HD * 2;
    size_t o2 = o1 + (size_t)HD3 * HD * 2;
    size_t o3 = o2 + (size_t)HD * HD * 2;
    size_t o4 = o3 + (size_t)HB * HH * HS * HDH * 2;
    size_t o5 = o4 + (size_t)HB * HH * HSF * HDH * 2;
    size_t o6 = o5 + (size_t)HB * HH * HSF * HDH * 2;
    u16* xb   = (u16*)(ws);
    u16* qkvb = (u16*)(ws + o1);
    u16* wob  = (u16*)(ws + o2);
    u16* qb   = (u16*)(ws + o3);
    u16* kb   = (u16*)(ws + o4);
    u16* vt   = (u16*)(ws + o5);
    u16* ctxb = (u16*)(ws + o6);

    k_cast<<<2048, 256, 0, stream>>>(x, xb, HM * HD / 4);
    k_cast<<<2048, 256, 0, stream>>>(qkv, qkvb, HD3 * HD / 4);
    k_cast<<<2048, 256, 0, stream>>>(wo, wob, HD * HD / 4);
    k_cache_copy<<<2048, 256, 0, stream>>>(kc, vc, kf, vf, kb, vt);

    k_gemm_bt<0><<<dim3(HM / 128, HD3 / 128), 256, 0, stream>>>(
        xb, qkvb, HD, nullptr, qb, kf, vf, kb, vt);

    k_attn<<<dim3(HS / 64, HB * HH), 256, 0, stream>>>(qb, kb, vt, ctxb, plp);

    k_gemm_bt<1><<<dim3(HM / 128, HD / 128), 256, 0, stream>>>(
        ctxb, wob, HD, out, nullptr, nullptr, nullptr, nullptr, nullptr);
}

// Round 2
// 263.295 us; speedup vs baseline: 1.5750x; 1.5750x over previous
//
#include <hip/hip_runtime.h>
#include <cstdint>

#define HB 2
#define HS 1024
#define HSF 2048
#define HH 16
#define HDH 128
#define HD 2048
#define HD3 6144
#define HM 2048  // HB*HS

typedef __attribute__((ext_vector_type(8))) short bf16x8;
typedef __attribute__((ext_vector_type(4))) float f32x4;
typedef unsigned short u16;
typedef unsigned int u32;

__device__ __forceinline__ u16 f2b(float f) {
    union { float f; u32 u; } v; v.f = f;
    u32 u = v.u;
    return (u16)((u + 0x7FFFu + ((u >> 16) & 1u)) >> 16);
}

__device__ __forceinline__ f32x4 mfma16x16(bf16x8 a, bf16x8 b, f32x4 c) {
    return __builtin_amdgcn_mfma_f32_16x16x32_bf16(a, b, c, 0, 0, 0);
}

#define GLD16(gp, lp) __builtin_amdgcn_global_load_lds( \
    (__attribute__((address_space(1))) void*)(gp), \
    (__attribute__((address_space(3))) void*)(lp), 16, 0, 0)

// ---------------- cast f32 -> bf16 (vectorized) ----------------
__global__ void k_cast(const float* __restrict__ src, u16* __restrict__ dst, int n4) {
    int i = blockIdx.x * blockDim.x + threadIdx.x;
    int st = gridDim.x * blockDim.x;
    for (; i < n4; i += st) {
        float4 v = ((const float4*)src)[i];
        ushort4 o;
        o.x = f2b(v.x); o.y = f2b(v.y); o.z = f2b(v.z); o.w = f2b(v.w);
        ((ushort4*)dst)[i] = o;
    }
}

// ---------------- copy caches into outputs + bf16 K + bf16 V^T ----------------
__global__ void k_cache_copy(const float* __restrict__ kc, const float* __restrict__ vc,
                             float* __restrict__ kf, float* __restrict__ vf,
                             u16* __restrict__ kb, u16* __restrict__ vt) {
    const int n4 = HB * HH * HS * HDH / 4;
    int i = blockIdx.x * blockDim.x + threadIdx.x;
    int st = gridDim.x * blockDim.x;
    for (; i < n4; i += st) {
        int e = i * 4;
        int bh = e / (HS * HDH);
        int rem = e - bh * (HS * HDH);   // s*128 + dh
        int s = rem >> 7, dh = rem & 127;
        float4 kv = ((const float4*)kc)[i];
        float4 vv = ((const float4*)vc)[i];
        size_t o = (size_t)bh * (HSF * HDH) + (size_t)rem;
        *(float4*)(kf + o) = kv;
        *(float4*)(vf + o) = vv;
        ushort4 kb4; kb4.x = f2b(kv.x); kb4.y = f2b(kv.y); kb4.z = f2b(kv.z); kb4.w = f2b(kv.w);
        *(ushort4*)(kb + o) = kb4;
        size_t vb = (size_t)bh * (HDH * HSF) + (size_t)dh * HSF + (size_t)s;
        vt[vb]           = f2b(vv.x);
        vt[vb + HSF]     = f2b(vv.y);
        vt[vb + 2 * HSF] = f2b(vv.z);
        vt[vb + 3 * HSF] = f2b(vv.w);
    }
}

// ---------------- bf16 GEMM: C[m,n] = sum_k A[m,k]*B[n,k] ----------------
// EPI=0: QKV scatter epilogue (N=6144).  EPI=1: plain fp32 C write (N=2048).
template<int EPI>
__global__ __launch_bounds__(256, 2) void k_gemm_bt(
    const u16* __restrict__ A, const u16* __restrict__ Bw, int K,
    float* __restrict__ outf,
    u16* __restrict__ qb, float* __restrict__ kf, float* __restrict__ vf,
    u16* __restrict__ kb, u16* __restrict__ vt)
{
    __shared__ __align__(16) u16 As[128 * 32];
    __shared__ __align__(16) u16 Bs[128 * 32];
    const int tid = threadIdx.x;
    const int w = tid >> 6, lane = tid & 63;
    const int wm = w >> 1, wn = w & 1;
    const int lcol = lane & 15, lhi = lane >> 4;
    const int m0 = blockIdx.x * 128, n0 = blockIdx.y * 128;

    const int srow = lane >> 2;        // 0..15
    const int scol = (lane & 3) * 8;   // 0,8,16,24
    const int c0 = w * 2, c1 = w * 2 + 1;
    const u16* Ag0 = A + (size_t)(m0 + c0 * 16 + srow) * K + scol;
    const u16* Ag1 = A + (size_t)(m0 + c1 * 16 + srow) * K + scol;
    const u16* Bg0 = Bw + (size_t)(n0 + c0 * 16 + srow) * K + scol;
    const u16* Bg1 = Bw + (size_t)(n0 + c1 * 16 + srow) * K + scol;
    u16* As0 = &As[c0 * 512]; u16* As1 = &As[c1 * 512];
    u16* Bs0 = &Bs[c0 * 512]; u16* Bs1 = &Bs[c1 * 512];

    f32x4 acc[4][4] = {};

    for (int k0 = 0; k0 < K; k0 += 32) {
        __syncthreads();
        GLD16(Ag0 + k0, As0);
        GLD16(Ag1 + k0, As1);
        GLD16(Bg0 + k0, Bs0);
        GLD16(Bg1 + k0, Bs1);
        __syncthreads();
        bf16x8 af[4], bfr[4];
        #pragma unroll
        for (int i = 0; i < 4; ++i)
            af[i] = *(const bf16x8*)&As[(wm * 64 + i * 16 + lcol) * 32 + lhi * 8];
        #pragma unroll
        for (int i = 0; i < 4; ++i)
            bfr[i] = *(const bf16x8*)&Bs[(wn * 64 + i * 16 + lcol) * 32 + lhi * 8];
        #pragma unroll
        for (int i = 0; i < 4; ++i)
            #pragma unroll
            for (int j = 0; j < 4; ++j)
                acc[i][j] = mfma16x16(af[i], bfr[j], acc[i][j]);
    }

    #pragma unroll
    for (int i = 0; i < 4; ++i) {
      #pragma unroll
      for (int j = 0; j < 4; ++j) {
        #pragma unroll
        for (int r = 0; r < 4; ++r) {
            int m = m0 + wm * 64 + i * 16 + lhi * 4 + r;
            int n = n0 + wn * 64 + j * 16 + lcol;
            float v = acc[i][j][r];
            if (EPI == 1) {
                outf[(size_t)m * HD + n] = v;
            } else {
                int b = m >> 10, s = m & 1023;
                int sec = n >> 11, e = n & 2047;
                int h = e >> 7, dh = e & 127;
                int bh = b * HH + h;
                if (sec == 0) {
                    qb[((size_t)bh * HS + s) * HDH + dh] = f2b(v);
                } else if (sec == 1) {
                    size_t idx = ((size_t)bh * HSF + HS + s) * HDH + dh;
                    kf[idx] = v; kb[idx] = f2b(v);
                } else {
                    size_t idx = ((size_t)bh * HSF + HS + s) * HDH + dh;
                    vf[idx] = v;
                    vt[((size_t)bh * HDH + dh) * HSF + HS + s] = f2b(v);
                }
            }
        }
      }
    }
}

// ---------------- flash attention: 4 waves, 64 q rows, LDS-staged KV ----------------
// Block: 4 waves, wave w owns q rows q0..q0+15. KV tile = 64 keys.
// K tile Ks[64][128] bf16 (row=key), V tile Vs[128][64] bf16 (row=dh), both
// XOR-swizzled (byte ^= (row&7)<<4) to kill the 16-way row-stride bank conflict.
// Reg-staged double pipeline: loads for tile t+1 issued before compute of t.
__global__ __launch_bounds__(256, 2) void k_attn(
    const u16* __restrict__ qb, const u16* __restrict__ kb,
    const u16* __restrict__ vt, u16* __restrict__ ctx,
    const int* __restrict__ plp)
{
    __shared__ __align__(16) u16 Ks[64 * 128];
    __shared__ __align__(16) u16 Vs[128 * 64];
    __shared__ __align__(16) u16 Pl[4][16][72];

    const int past = *plp;                 // 1024
    const int tid = threadIdx.x, w = tid >> 6, lane = tid & 63;
    const int lcol = lane & 15, lhi = lane >> 4;

    // XCD-bijective mapping: all 16 q-blocks of one head on one XCD (id%8).
    const int bid = blockIdx.x;            // 0..511
    const int rest = bid >> 3;
    const int qblk = rest & 15;
    const int bh = (bid & 7) + 8 * (rest >> 4);
    const int q0 = qblk * 64 + w * 16;
    const float sc2 = 0.08838834764831845f * 1.4426950408889634f; // scale*log2e

    const u16* qx = qb + (size_t)bh * HS * HDH;
    const u16* kx = kb + (size_t)bh * HSF * HDH;
    const u16* vx = vt + (size_t)bh * HDH * HSF;

    // Q fragments (once)
    bf16x8 aq[4];
    #pragma unroll
    for (int kc = 0; kc < 4; ++kc)
        aq[kc] = *(const bf16x8*)&qx[(size_t)(q0 + lcol) * HDH + kc * 32 + lhi * 8];

    // staging geometry: wave w stages K rows w*16..+15 (4 loads x 4 rows),
    // V rows (dh) w*32..+31 (4 loads x 8 rows)
    const int krow = w * 16 + (lane >> 4);     // + q*4
    const int kcol = (lane & 15) * 8;
    const int vrow = w * 32 + (lane >> 3);     // + q*8
    const int vcol = (lane & 7) * 8;
    const u16* kgbase = kx + (size_t)krow * HDH + kcol;
    const u16* vgbase = vx + (size_t)vrow * HSF + vcol;
    int kwb[4], vwb[4];
    #pragma unroll
    for (int q = 0; q < 4; ++q) {
        int r = krow + q * 4;
        kwb[q] = (r * 256 + kcol * 2) ^ ((r & 7) << 4);
    }
    #pragma unroll
    for (int q = 0; q < 4; ++q) {
        int r = vrow + q * 8;
        vwb[q] = (r * 128 + vcol * 2) ^ ((r & 7) << 4);
    }

    bf16x8 kst[4], vst[4];
    auto stage_load = [&](int j0_) {
        #pragma unroll
        for (int q = 0; q < 4; ++q)
            kst[q] = *(const bf16x8*)(kgbase + (size_t)(j0_ + q * 4) * HDH);
        #pragma unroll
        for (int q = 0; q < 4; ++q)
            vst[q] = *(const bf16x8*)(vgbase + (size_t)q * 8 * HSF + j0_);
    };
    auto stage_write = [&]() {
        #pragma unroll
        for (int q = 0; q < 4; ++q)
            *(bf16x8*)((char*)Ks + kwb[q]) = kst[q];
        #pragma unroll
        for (int q = 0; q < 4; ++q)
            *(bf16x8*)((char*)Vs + vwb[q]) = vst[q];
    };

    f32x4 o[8] = {};
    f32x4 mr = {-3e38f, -3e38f, -3e38f, -3e38f};
    f32x4 lr = {};

    int nkt = (qblk * 64 + 64 + past + 63) >> 6;
    if (nkt > HSF / 64) nkt = HSF / 64;

    stage_load(0);
    for (int kt = 0; kt < nkt; ++kt) {
        const int j0 = kt * 64;
        __syncthreads();                 // all waves done reading prev tile
        stage_write();                   // regs (tile t) -> LDS
        if (kt + 1 < nkt) stage_load(j0 + 64);   // prefetch t+1 under compute
        __syncthreads();                 // tile t visible

        // ---- QK^T: 16 ds_read + 16 MFMA ----
        f32x4 sf[4] = {};
        #pragma unroll
        for (int sub = 0; sub < 4; ++sub) {
            int row = sub * 16 + lcol;
            int rb = row * 256, sw = (row & 7) << 4;
            #pragma unroll
            for (int kc = 0; kc < 4; ++kc) {
                bf16x8 bk = *(const bf16x8*)((const char*)Ks + ((rb + kc * 64 + lhi * 16) ^ sw));
                sf[sub] = mfma16x16(aq[kc], bk, sf[sub]);
            }
        }

        // ---- vectorized online softmax (4 rows in flight) ----
        f32x4 p[4];
        #pragma unroll
        for (int sub = 0; sub < 4; ++sub)
            p[sub] = sf[sub] * sc2;
        if (j0 + 63 > q0 + past) {       // only boundary tiles pay the mask
            #pragma unroll
            for (int sub = 0; sub < 4; ++sub) {
                int j = j0 + sub * 16 + lcol;
                #pragma unroll
                for (int r = 0; r < 4; ++r)
                    if (j > q0 + lhi * 4 + r + past) p[sub][r] = -3e38f;
            }
        }
        f32x4 mx;
        #pragma unroll
        for (int r = 0; r < 4; ++r)
            mx[r] = fmaxf(fmaxf(p[0][r], p[1][r]), fmaxf(p[2][r], p[3][r]));
        #pragma unroll
        for (int sh = 1; sh < 16; sh <<= 1)
            #pragma unroll
            for (int r = 0; r < 4; ++r)
                mx[r] = fmaxf(mx[r], __shfl_xor(mx[r], sh, 64));
        f32x4 alpha, ps = {};
        #pragma unroll
        for (int r = 0; r < 4; ++r) {
            float mnew = fmaxf(mr[r], mx[r]);
            alpha[r] = exp2f(mr[r] - mnew);
            mr[r] = mnew;
        }
        #pragma unroll
        for (int sub = 0; sub < 4; ++sub)
            #pragma unroll
            for (int r = 0; r < 4; ++r) {
                p[sub][r] = exp2f(p[sub][r] - mr[r]);
                ps[r] += p[sub][r];
            }
        #pragma unroll
        for (int sh = 1; sh < 16; sh <<= 1)
            #pragma unroll
            for (int r = 0; r < 4; ++r)
                ps[r] += __shfl_xor(ps[r], sh, 64);
        #pragma unroll
        for (int r = 0; r < 4; ++r)
            lr[r] = lr[r] * alpha[r] + ps[r];
        #pragma unroll
        for (int sub = 0; sub < 4; ++sub)
            #pragma unroll
            for (int r = 0; r < 4; ++r)
                Pl[w][lhi * 4 + r][sub * 16 + lcol] = f2b(p[sub][r]);
        #pragma unroll
        for (int d = 0; d < 8; ++d)
            #pragma unroll
            for (int r = 0; r < 4; ++r)
                o[d][r] *= alpha[r];

        // ---- PV: 16 ds_read + 16 MFMA (same-wave DS order for Pl) ----
        bf16x8 ap0 = *(const bf16x8*)&Pl[w][lcol][lhi * 8];
        bf16x8 ap1 = *(const bf16x8*)&Pl[w][lcol][32 + lhi * 8];
        #pragma unroll
        for (int d = 0; d < 8; ++d) {
            int row = d * 16 + lcol;
            int rb = row * 128, sw = (row & 7) << 4;
            bf16x8 bv0 = *(const bf16x8*)((const char*)Vs + ((rb + lhi * 16) ^ sw));
            bf16x8 bv1 = *(const bf16x8*)((const char*)Vs + ((rb + 64 + lhi * 16) ^ sw));
            o[d] = mfma16x16(ap0, bv0, o[d]);
            o[d] = mfma16x16(ap1, bv1, o[d]);
        }
    }

    const int b = bh >> 4, h = bh & 15;
    #pragma unroll
    for (int r = 0; r < 4; ++r) {
        float inv = 1.f / lr[r];
        int s = q0 + lhi * 4 + r;
        #pragma unroll
        for (int d = 0; d < 8; ++d)
            ctx[((size_t)(b * HS + s)) * HD + h * HDH + d * 16 + lcol] = f2b(o[d][r] * inv);
    }
}

// ---------------- launch ----------------
extern "C" void kernel_launch(void* const* d_in, const int* in_sizes, int n_in,
                              void* d_out, int out_size, void* d_ws, size_t ws_size,
                              hipStream_t stream) {
    const float* x   = (const float*)d_in[0];
    const float* kc  = (const float*)d_in[1];
    const float* vc  = (const float*)d_in[2];
    const float* qkv = (const float*)d_in[3];
    const float* wo  = (const float*)d_in[4];
    const int* plp   = (const int*)d_in[5];

    float* out = (float*)d_out;
    float* kf  = out + (size_t)HB * HS * HD;        // k_full
    float* vf  = kf + (size_t)HB * HH * HSF * HDH;  // v_full

    char* ws = (char*)d_ws;
    size_t o1 = (size_t)HM * HD * 2;
    size_t o2 = o1 + (size_t)HD3 * HD * 2;
    size_t o3 = o2 + (size_t)HD * HD * 2;
    size_t o4 = o3 + (size_t)HB * HH * HS * HDH * 2;
    size_t o5 = o4 + (size_t)HB * HH * HSF * HDH * 2;
    size_t o6 = o5 + (size_t)HB * HH * HSF * HDH * 2;
    u16* xb   = (u16*)(ws);
    u16* qkvb = (u16*)(ws + o1);
    u16* wob  = (u16*)(ws + o2);
    u16* qb   = (u16*)(ws + o3);
    u16* kb   = (u16*)(ws + o4);
    u16* vt   = (u16*)(ws + o5);
    u16* ctxb = (u16*)(ws + o6);

    k_cast<<<2048, 256, 0, stream>>>(x, xb, HM * HD / 4);
    k_cast<<<2048, 256, 0, stream>>>(qkv, qkvb, HD3 * HD / 4);
    k_cast<<<2048, 256, 0, stream>>>(wo, wob, HD * HD / 4);
    k_cache_copy<<<2048, 256, 0, stream>>>(kc, vc, kf, vf, kb, vt);

    k_gemm_bt<0><<<dim3(HM / 128, HD3 / 128), 256, 0, stream>>>(
        xb, qkvb, HD, nullptr, qb, kf, vf, kb, vt);

    k_attn<<<512, 256, 0, stream>>>(qb, kb, vt, ctxb, plp);

    k_gemm_bt<1><<<dim3(HM / 128, HD / 128), 256, 0, stream>>>(
        ctxb, wob, HD, out, nullptr, nullptr, nullptr, nullptr, nullptr);
}

// Round 3
// 253.792 us; speedup vs baseline: 1.6340x; 1.0374x over previous
//
#include <hip/hip_runtime.h>
#include <cstdint>

#define HB 2
#define HS 1024
#define HSF 2048
#define HH 16
#define HDH 128
#define HD 2048
#define HD3 6144
#define HM 2048  // HB*HS

typedef __attribute__((ext_vector_type(8))) short bf16x8;
typedef __attribute__((ext_vector_type(4))) float f32x4;
typedef unsigned short u16;
typedef unsigned int u32;

__device__ __forceinline__ u16 f2b(float f) {
    union { float f; u32 u; } v; v.f = f;
    u32 u = v.u;
    return (u16)((u + 0x7FFFu + ((u >> 16) & 1u)) >> 16);
}

__device__ __forceinline__ f32x4 mfma16x16(bf16x8 a, bf16x8 b, f32x4 c) {
    return __builtin_amdgcn_mfma_f32_16x16x32_bf16(a, b, c, 0, 0, 0);
}

#define GLD16(gp, lp) __builtin_amdgcn_global_load_lds( \
    (__attribute__((address_space(1))) void*)(gp), \
    (__attribute__((address_space(3))) void*)(lp), 16, 0, 0)

// ---------------- cast f32 -> bf16 (vectorized) ----------------
__global__ void k_cast(const float* __restrict__ src, u16* __restrict__ dst, int n4) {
    int i = blockIdx.x * blockDim.x + threadIdx.x;
    int st = gridDim.x * blockDim.x;
    for (; i < n4; i += st) {
        float4 v = ((const float4*)src)[i];
        ushort4 o;
        o.x = f2b(v.x); o.y = f2b(v.y); o.z = f2b(v.z); o.w = f2b(v.w);
        ((ushort4*)dst)[i] = o;
    }
}

// ---------------- copy caches into outputs + bf16 K + bf16 V^T ----------------
__global__ void k_cache_copy(const float* __restrict__ kc, const float* __restrict__ vc,
                             float* __restrict__ kf, float* __restrict__ vf,
                             u16* __restrict__ kb, u16* __restrict__ vt) {
    const int n4 = HB * HH * HS * HDH / 4;
    int i = blockIdx.x * blockDim.x + threadIdx.x;
    int st = gridDim.x * blockDim.x;
    for (; i < n4; i += st) {
        int e = i * 4;
        int bh = e / (HS * HDH);
        int rem = e - bh * (HS * HDH);   // s*128 + dh
        int s = rem >> 7, dh = rem & 127;
        float4 kv = ((const float4*)kc)[i];
        float4 vv = ((const float4*)vc)[i];
        size_t o = (size_t)bh * (HSF * HDH) + (size_t)rem;
        *(float4*)(kf + o) = kv;
        *(float4*)(vf + o) = vv;
        ushort4 kb4; kb4.x = f2b(kv.x); kb4.y = f2b(kv.y); kb4.z = f2b(kv.z); kb4.w = f2b(kv.w);
        *(ushort4*)(kb + o) = kb4;
        size_t vb = (size_t)bh * (HDH * HSF) + (size_t)dh * HSF + (size_t)s;
        vt[vb]           = f2b(vv.x);
        vt[vb + HSF]     = f2b(vv.y);
        vt[vb + 2 * HSF] = f2b(vv.z);
        vt[vb + 3 * HSF] = f2b(vv.w);
    }
}

// ---------------- bf16 GEMM: C[m,n] = sum_k A[m,k]*B[n,k] ----------------
template<int EPI>
__global__ __launch_bounds__(256, 2) void k_gemm_bt(
    const u16* __restrict__ A, const u16* __restrict__ Bw, int K,
    float* __restrict__ outf,
    u16* __restrict__ qb, float* __restrict__ kf, float* __restrict__ vf,
    u16* __restrict__ kb, u16* __restrict__ vt)
{
    __shared__ __align__(16) u16 As[128 * 32];
    __shared__ __align__(16) u16 Bs[128 * 32];
    const int tid = threadIdx.x;
    const int w = tid >> 6, lane = tid & 63;
    const int wm = w >> 1, wn = w & 1;
    const int lcol = lane & 15, lhi = lane >> 4;
    const int m0 = blockIdx.x * 128, n0 = blockIdx.y * 128;

    const int srow = lane >> 2;
    const int scol = (lane & 3) * 8;
    const int c0 = w * 2, c1 = w * 2 + 1;
    const u16* Ag0 = A + (size_t)(m0 + c0 * 16 + srow) * K + scol;
    const u16* Ag1 = A + (size_t)(m0 + c1 * 16 + srow) * K + scol;
    const u16* Bg0 = Bw + (size_t)(n0 + c0 * 16 + srow) * K + scol;
    const u16* Bg1 = Bw + (size_t)(n0 + c1 * 16 + srow) * K + scol;
    u16* As0 = &As[c0 * 512]; u16* As1 = &As[c1 * 512];
    u16* Bs0 = &Bs[c0 * 512]; u16* Bs1 = &Bs[c1 * 512];

    f32x4 acc[4][4] = {};

    for (int k0 = 0; k0 < K; k0 += 32) {
        __syncthreads();
        GLD16(Ag0 + k0, As0);
        GLD16(Ag1 + k0, As1);
        GLD16(Bg0 + k0, Bs0);
        GLD16(Bg1 + k0, Bs1);
        __syncthreads();
        bf16x8 af[4], bfr[4];
        #pragma unroll
        for (int i = 0; i < 4; ++i)
            af[i] = *(const bf16x8*)&As[(wm * 64 + i * 16 + lcol) * 32 + lhi * 8];
        #pragma unroll
        for (int i = 0; i < 4; ++i)
            bfr[i] = *(const bf16x8*)&Bs[(wn * 64 + i * 16 + lcol) * 32 + lhi * 8];
        #pragma unroll
        for (int i = 0; i < 4; ++i)
            #pragma unroll
            for (int j = 0; j < 4; ++j)
                acc[i][j] = mfma16x16(af[i], bfr[j], acc[i][j]);
    }

    #pragma unroll
    for (int i = 0; i < 4; ++i) {
      #pragma unroll
      for (int j = 0; j < 4; ++j) {
        #pragma unroll
        for (int r = 0; r < 4; ++r) {
            int m = m0 + wm * 64 + i * 16 + lhi * 4 + r;
            int n = n0 + wn * 64 + j * 16 + lcol;
            float v = acc[i][j][r];
            if (EPI == 1) {
                outf[(size_t)m * HD + n] = v;
            } else {
                int b = m >> 10, s = m & 1023;
                int sec = n >> 11, e = n & 2047;
                int h = e >> 7, dh = e & 127;
                int bh = b * HH + h;
                if (sec == 0) {
                    qb[((size_t)bh * HS + s) * HDH + dh] = f2b(v);
                } else if (sec == 1) {
                    size_t idx = ((size_t)bh * HSF + HS + s) * HDH + dh;
                    kf[idx] = v; kb[idx] = f2b(v);
                } else {
                    size_t idx = ((size_t)bh * HSF + HS + s) * HDH + dh;
                    vf[idx] = v;
                    vt[((size_t)bh * HDH + dh) * HSF + HS + s] = f2b(v);
                }
            }
        }
      }
    }
}

// ---------------- flash attention: swapped-QK^T, in-register softmax ----------------
// 4 waves x 16 q rows, KV tile 64, double-buffered LDS (1 barrier/tile).
// S^T = mfma(K,Q): lane holds P[k=sub*16+lhi*4+r][q=q0+lcol] -> softmax in-lane +
// 2 shfl_xor. PV: O^T = mfma(V^T, P^T); P B-frags built via cvt_pk + shfl.
__global__ __launch_bounds__(256) void k_attn(
    const u16* __restrict__ qb, const u16* __restrict__ kb,
    const u16* __restrict__ vt, u16* __restrict__ ctx,
    const int* __restrict__ plp)
{
    __shared__ __align__(16) u16 Ks[2 * 64 * 128];
    __shared__ __align__(16) u16 Vs[2 * 128 * 64];

    const int past = *plp;                 // 1024
    const int tid = threadIdx.x, w = tid >> 6, lane = tid & 63;
    const int lcol = lane & 15, lhi = lane >> 4;

    const int bid = blockIdx.x;            // 0..511
    const int rest = bid >> 3;
    const int qblk = rest & 15;
    const int bh = (bid & 7) + 8 * (rest >> 4);
    const int q0 = qblk * 64 + w * 16;
    const float sc2 = 0.08838834764831845f * 1.4426950408889634f; // scale*log2e

    const u16* qx = qb + (size_t)bh * HS * HDH;
    const u16* kx = kb + (size_t)bh * HSF * HDH;
    const u16* vx = vt + (size_t)bh * HDH * HSF;

    // Q fragments (B-operand): lane holds Q[q0+lcol][kc*32+lhi*8 ..+7]
    bf16x8 aq[4];
    #pragma unroll
    for (int kc = 0; kc < 4; ++kc)
        aq[kc] = *(const bf16x8*)&qx[(size_t)(q0 + lcol) * HDH + kc * 32 + lhi * 8];

    // staging geometry (per wave): K rows w*16..+15, V rows (dh) w*32..+31
    const int krow = w * 16 + (lane >> 4);
    const int kcol = (lane & 15) * 8;
    const int vrow = w * 32 + (lane >> 3);
    const int vcol = (lane & 7) * 8;
    const u16* kgbase = kx + (size_t)krow * HDH + kcol;
    const u16* vgbase = vx + (size_t)vrow * HSF + vcol;
    int kwb[4], vwb[4];
    #pragma unroll
    for (int q = 0; q < 4; ++q) {
        int r = krow + q * 4;
        kwb[q] = (r * 256 + kcol * 2) ^ ((r & 7) << 4);
    }
    #pragma unroll
    for (int q = 0; q < 4; ++q) {
        int r = vrow + q * 8;
        vwb[q] = (r * 128 + vcol * 2) ^ ((r & 7) << 4);
    }

    bf16x8 kst[4], vst[4];
    auto stage_load = [&](int j0_) {
        #pragma unroll
        for (int q = 0; q < 4; ++q)
            kst[q] = *(const bf16x8*)(kgbase + (size_t)(j0_ + q * 4) * HDH);
        #pragma unroll
        for (int q = 0; q < 4; ++q)
            vst[q] = *(const bf16x8*)(vgbase + (size_t)q * 8 * HSF + j0_);
    };
    auto stage_write = [&](int bo) {
        #pragma unroll
        for (int q = 0; q < 4; ++q)
            *(bf16x8*)((char*)Ks + bo + kwb[q]) = kst[q];
        #pragma unroll
        for (int q = 0; q < 4; ++q)
            *(bf16x8*)((char*)Vs + bo + vwb[q]) = vst[q];
    };

    f32x4 o[8] = {};
    float mr = -3e38f, lr = 0.f;
    const int q = q0 + lcol;               // this lane's q row

    int nkt = (qblk * 64 + 64 + past + 63) >> 6;
    if (nkt > HSF / 64) nkt = HSF / 64;

    stage_load(0);
    stage_write(0);
    __syncthreads();
    int bufo = 0;

    for (int kt = 0; kt < nkt; ++kt) {
        const int j0 = kt * 64;
        if (kt + 1 < nkt) stage_load(j0 + 64);   // prefetch t+1 into regs

        // ---- QK^T (swapped): S^T[k][q], 16 ds_read + 16 MFMA ----
        const char* ksb = (const char*)Ks + bufo;
        f32x4 sf[4] = {};
        __builtin_amdgcn_s_setprio(1);
        #pragma unroll
        for (int sub = 0; sub < 4; ++sub) {
            int row = sub * 16 + lcol;
            int rb = row * 256, sw = (row & 7) << 4;
            #pragma unroll
            for (int kc = 0; kc < 4; ++kc) {
                bf16x8 ak = *(const bf16x8*)(ksb + ((rb + kc * 64 + lhi * 16) ^ sw));
                sf[sub] = mfma16x16(ak, aq[kc], sf[sub]);
            }
        }
        __builtin_amdgcn_s_setprio(0);

        // ---- in-lane online softmax (lane owns one q row, 16 k values) ----
        f32x4 p4[4];
        #pragma unroll
        for (int sub = 0; sub < 4; ++sub)
            p4[sub] = sf[sub] * sc2;
        if (j0 + 63 > q0 + past) {
            #pragma unroll
            for (int sub = 0; sub < 4; ++sub)
                #pragma unroll
                for (int r = 0; r < 4; ++r)
                    if (j0 + sub * 16 + lhi * 4 + r > q + past) p4[sub][r] = -3e38f;
        }
        float mx = -3e38f;
        #pragma unroll
        for (int sub = 0; sub < 4; ++sub) {
            float a = fmaxf(p4[sub][0], p4[sub][1]);
            float b2 = fmaxf(p4[sub][2], p4[sub][3]);
            mx = fmaxf(mx, fmaxf(a, b2));
        }
        mx = fmaxf(mx, __shfl_xor(mx, 16, 64));
        mx = fmaxf(mx, __shfl_xor(mx, 32, 64));
        float mnew = fmaxf(mr, mx);
        float alpha = exp2f(mr - mnew);
        float ps = 0.f;
        #pragma unroll
        for (int sub = 0; sub < 4; ++sub)
            #pragma unroll
            for (int r = 0; r < 4; ++r) {
                p4[sub][r] = exp2f(p4[sub][r] - mnew);
                ps += p4[sub][r];
            }
        ps += __shfl_xor(ps, 16, 64);
        ps += __shfl_xor(ps, 32, 64);
        lr = lr * alpha + ps;
        mr = mnew;
        #pragma unroll
        for (int t = 0; t < 8; ++t)
            o[t] *= alpha;

        // ---- build P^T B-frags in-register: 8 cvt_pk + 16 shfl + 8 select ----
        u32 w0[4], w1[4];
        #pragma unroll
        for (int sub = 0; sub < 4; ++sub) {
            asm("v_cvt_pk_bf16_f32 %0, %1, %2" : "=v"(w0[sub]) : "v"(p4[sub][0]), "v"(p4[sub][1]));
            asm("v_cvt_pk_bf16_f32 %0, %1, %2" : "=v"(w1[sub]) : "v"(p4[sub][2]), "v"(p4[sub][3]));
        }
        const int srcA = lcol + ((lhi & 1) << 5);   // lane of lh_s=(lhi&1)*2
        const int srcB = srcA + 16;                 // lane of lh_s+1
        const bool hi = (lhi & 2);
        bf16x8 pb[2];
        #pragma unroll
        for (int c = 0; c < 2; ++c) {
            u32 b0a = __shfl((int)w0[2 * c], srcA, 64), b0b = __shfl((int)w0[2 * c + 1], srcA, 64);
            u32 b1a = __shfl((int)w1[2 * c], srcA, 64), b1b = __shfl((int)w1[2 * c + 1], srcA, 64);
            u32 b2a = __shfl((int)w0[2 * c], srcB, 64), b2b = __shfl((int)w0[2 * c + 1], srcB, 64);
            u32 b3a = __shfl((int)w1[2 * c], srcB, 64), b3b = __shfl((int)w1[2 * c + 1], srcB, 64);
            union { u32 u[4]; bf16x8 v; } cvt;
            cvt.u[0] = hi ? b0b : b0a;
            cvt.u[1] = hi ? b1b : b1a;
            cvt.u[2] = hi ? b2b : b2a;
            cvt.u[3] = hi ? b3b : b3a;
            pb[c] = cvt.v;
        }

        // ---- PV: O^T += V^T * P^T, 16 ds_read + 16 MFMA ----
        const char* vsb = (const char*)Vs + bufo;
        __builtin_amdgcn_s_setprio(1);
        #pragma unroll
        for (int t = 0; t < 8; ++t) {
            int row = t * 16 + lcol;
            int rb = row * 128, sw = (row & 7) << 4;
            bf16x8 av0 = *(const bf16x8*)(vsb + ((rb + lhi * 16) ^ sw));
            bf16x8 av1 = *(const bf16x8*)(vsb + ((rb + 64 + lhi * 16) ^ sw));
            o[t] = mfma16x16(av0, pb[0], o[t]);
            o[t] = mfma16x16(av1, pb[1], o[t]);
        }
        __builtin_amdgcn_s_setprio(0);

        if (kt + 1 < nkt) stage_write(bufo ^ 16384);  // other buffer, no WAR
        __syncthreads();
        bufo ^= 16384;
    }

    // epilogue: lane owns q row; o[t][r] = O[q][d = t*16 + lhi*4 + r]
    const int b = bh >> 4, h = bh & 15;
    float inv = 1.f / lr;
    u16* crow = ctx + ((size_t)(b * HS + q)) * HD + h * HDH;
    #pragma unroll
    for (int t = 0; t < 8; ++t) {
        ushort4 wv;
        wv.x = f2b(o[t][0] * inv);
        wv.y = f2b(o[t][1] * inv);
        wv.z = f2b(o[t][2] * inv);
        wv.w = f2b(o[t][3] * inv);
        *(ushort4*)(crow + t * 16 + lhi * 4) = wv;
    }
}

// ---------------- launch ----------------
extern "C" void kernel_launch(void* const* d_in, const int* in_sizes, int n_in,
                              void* d_out, int out_size, void* d_ws, size_t ws_size,
                              hipStream_t stream) {
    const float* x   = (const float*)d_in[0];
    const float* kc  = (const float*)d_in[1];
    const float* vc  = (const float*)d_in[2];
    const float* qkv = (const float*)d_in[3];
    const float* wo  = (const float*)d_in[4];
    const int* plp   = (const int*)d_in[5];

    float* out = (float*)d_out;
    float* kf  = out + (size_t)HB * HS * HD;        // k_full
    float* vf  = kf + (size_t)HB * HH * HSF * HDH;  // v_full

    char* ws = (char*)d_ws;
    size_t o1 = (size_t)HM * HD * 2;
    size_t o2 = o1 + (size_t)HD3 * HD * 2;
    size_t o3 = o2 + (size_t)HD * HD * 2;
    size_t o4 = o3 + (size_t)HB * HH * HS * HDH * 2;
    size_t o5 = o4 + (size_t)HB * HH * HSF * HDH * 2;
    size_t o6 = o5 + (size_t)HB * HH * HSF * HDH * 2;
    u16* xb   = (u16*)(ws);
    u16* qkvb = (u16*)(ws + o1);
    u16* wob  = (u16*)(ws + o2);
    u16* qb   = (u16*)(ws + o3);
    u16* kb   = (u16*)(ws + o4);
    u16* vt   = (u16*)(ws + o5);
    u16* ctxb = (u16*)(ws + o6);

    k_cast<<<2048, 256, 0, stream>>>(x, xb, HM * HD / 4);
    k_cast<<<2048, 256, 0, stream>>>(qkv, qkvb, HD3 * HD / 4);
    k_cast<<<2048, 256, 0, stream>>>(wo, wob, HD * HD / 4);
    k_cache_copy<<<2048, 256, 0, stream>>>(kc, vc, kf, vf, kb, vt);

    k_gemm_bt<0><<<dim3(HM / 128, HD3 / 128), 256, 0, stream>>>(
        xb, qkvb, HD, nullptr, qb, kf, vf, kb, vt);

    k_attn<<<512, 256, 0, stream>>>(qb, kb, vt, ctxb, plp);

    k_gemm_bt<1><<<dim3(HM / 128, HD / 128), 256, 0, stream>>>(
        ctxb, wob, HD, out, nullptr, nullptr, nullptr, nullptr, nullptr);
}